// Round 1
// baseline (2616.122 us; speedup 1.0000x reference)
//
#include <hip/hip_runtime.h>
#include <cmath>

// BiDirectionalSpatialMamba: lin+GELU -> GRU(fwd & bwd over P) -> proj+residual -> LN
// B=8 T=16 P=1024 H=256, D_INNER=512, 3H=768. M = B*T*P = 131072 rows.

typedef _Float16 h8  __attribute__((ext_vector_type(8)));
typedef _Float16 h2v __attribute__((ext_vector_type(2)));
typedef float    f32x4 __attribute__((ext_vector_type(4)));

#define MTOT 131072L
#define PSEQ 1024

#if defined(__has_builtin)
#if __has_builtin(__builtin_amdgcn_fdot2)
#define HAVE_FDOT2 1
#endif
#endif

__device__ __forceinline__ float fdot2(h2v a, h2v b, float c) {
#ifdef HAVE_FDOT2
    return __builtin_amdgcn_fdot2(a, b, c, false);
#else
    return c + (float)a[0] * (float)b[0] + (float)a[1] * (float)b[1];
#endif
}

// ---------------- GEMM: C[M x N] = A[M x K] @ B[K x N] + bias, f16 MFMA ----------
// MODE 0: A fp32 (x),   K=256 N=512, epilogue GELU(exact) -> f16 (h1)
// MODE 1: A f16 (h1),   K=512 N=768, epilogue +b_ih       -> f16 (gi)
// MODE 2: A cat f16,    K=512 N=256, epilogue +b +x       -> f32 (pre-LN)
template <int MODE>
__global__ __launch_bounds__(256) void k_gemm(
    const void* __restrict__ Aa_, const void* __restrict__ Ab_,
    const float* __restrict__ B, const float* __restrict__ bias,
    const float* __restrict__ xres, void* __restrict__ out_)
{
    constexpr int K = (MODE == 0) ? 256 : 512;
    constexpr int N = (MODE == 0) ? 512 : (MODE == 1 ? 768 : 256);

    __shared__ __align__(16) _Float16 Al[64][40];  // [m][k], pad 32->40 (bank spread)
    __shared__ __align__(16) _Float16 Bl[64][40];  // [n][k]

    const int tid  = threadIdx.x;
    const int lane = tid & 63;
    const int wave = tid >> 6;
    const int wm = wave >> 1, wn = wave & 1;
    const long bm0 = (long)blockIdx.x * 64;
    const int  bn0 = blockIdx.y * 64;

    const int sm  = tid >> 2;          // A staging: row
    const int ska = (tid & 3) * 8;     // A staging: k offset
    const int sn  = tid & 63;          // B staging: col
    const int skb = (tid >> 6) * 8;    // B staging: k offset

    f32x4 acc[2][2] = {};

    for (int kt = 0; kt < K / 32; ++kt) {
        h8 av;
        if constexpr (MODE == 0) {
            const float* ap = (const float*)Aa_ + (bm0 + sm) * 256 + kt * 32 + ska;
            #pragma unroll
            for (int i = 0; i < 8; ++i) av[i] = (_Float16)ap[i];
        } else if constexpr (MODE == 1) {
            av = *(const h8*)((const _Float16*)Aa_ + (bm0 + sm) * 512 + kt * 32 + ska);
        } else {
            const _Float16* src = (kt < 8) ? (const _Float16*)Aa_ : (const _Float16*)Ab_;
            av = *(const h8*)(src + (bm0 + sm) * 256 + (kt & 7) * 32 + ska);
        }
        *(h8*)&Al[sm][ska] = av;

        h8 bv;
        #pragma unroll
        for (int i = 0; i < 8; ++i)
            bv[i] = (_Float16)B[(long)(kt * 32 + skb + i) * N + bn0 + sn];
        *(h8*)&Bl[sn][skb] = bv;

        __syncthreads();

        const int fr = lane & 15, fg = lane >> 4;
        h8 a0 = *(const h8*)&Al[wm * 32 +      fr][fg * 8];
        h8 a1 = *(const h8*)&Al[wm * 32 + 16 + fr][fg * 8];
        h8 b0 = *(const h8*)&Bl[wn * 32 +      fr][fg * 8];
        h8 b1 = *(const h8*)&Bl[wn * 32 + 16 + fr][fg * 8];
        acc[0][0] = __builtin_amdgcn_mfma_f32_16x16x32_f16(a0, b0, acc[0][0], 0, 0, 0);
        acc[0][1] = __builtin_amdgcn_mfma_f32_16x16x32_f16(a0, b1, acc[0][1], 0, 0, 0);
        acc[1][0] = __builtin_amdgcn_mfma_f32_16x16x32_f16(a1, b0, acc[1][0], 0, 0, 0);
        acc[1][1] = __builtin_amdgcn_mfma_f32_16x16x32_f16(a1, b1, acc[1][1], 0, 0, 0);

        __syncthreads();
    }

    const int fr = lane & 15, fg = lane >> 4;
    #pragma unroll
    for (int fm = 0; fm < 2; ++fm)
    #pragma unroll
    for (int fn = 0; fn < 2; ++fn)
    #pragma unroll
    for (int r = 0; r < 4; ++r) {
        long row = bm0 + wm * 32 + fm * 16 + fg * 4 + r;
        int  col = bn0 + wn * 32 + fn * 16 + fr;
        float v = acc[fm][fn][r] + bias[col];
        if constexpr (MODE == 0) {
            v = 0.5f * v * (1.0f + erff(v * 0.70710678118654752f));
            ((_Float16*)out_)[row * (long)N + col] = (_Float16)v;
        } else if constexpr (MODE == 1) {
            ((_Float16*)out_)[row * (long)N + col] = (_Float16)v;
        } else {
            v += xres[row * 256 + col];
            ((float*)out_)[row * 256 + col] = v;
        }
    }
}

// ---------------- GRU recurrence: 256 blocks = 128 seq x 2 directions ------------
// 768 threads: thread j owns column j of W_hh (128 packed half2 in VGPRs).
// h (256 f16) broadcast from LDS; v_dot2_f32_f16; 2 barriers/step; gi prefetch.
__global__ __launch_bounds__(768, 3) void k_gru(
    const _Float16* __restrict__ gif, const _Float16* __restrict__ gib,
    const float* __restrict__ Whhf, const float* __restrict__ Whhb,
    const float* __restrict__ bhhf, const float* __restrict__ bhhb,
    _Float16* __restrict__ hof, _Float16* __restrict__ hob)
{
    const int bid = blockIdx.x;
    const int branch = bid & 1;
    const int seq = bid >> 1;
    const int j = threadIdx.x;

    const _Float16* gi = (branch ? gib : gif) + (long)seq * PSEQ * 768;
    const float* Whh = branch ? Whhb : Whhf;
    const float* bhh = branch ? bhhb : bhhf;
    _Float16* ho = (branch ? hob : hof) + (long)seq * PSEQ * 256;

    h2v w[128];
    #pragma unroll
    for (int kk = 0; kk < 128; ++kk) {
        h2v t;
        t[0] = (_Float16)Whh[(2 * kk) * 768 + j];
        t[1] = (_Float16)Whh[(2 * kk + 1) * 768 + j];
        w[kk] = t;
    }
    const float bj = bhh[j];

    __shared__ __align__(16) _Float16 sh_h[256];
    __shared__ float a_lds[768];
    __shared__ float gin_lds[256];

    if (j < 256) sh_h[j] = (_Float16)0.f;
    __syncthreads();

    const int dir = branch ? -1 : 1;
    int p = branch ? (PSEQ - 1) : 0;
    float gcur = (float)gi[(long)p * 768 + j];
    float hu = 0.f;

    for (int step = 0; step < PSEQ; ++step) {
        float gnxt = 0.f;
        if (step < PSEQ - 1) gnxt = (float)gi[(long)(p + dir) * 768 + j];

        float acc0 = 0.f, acc1 = 0.f, acc2 = 0.f, acc3 = 0.f;
        const float4* h4 = (const float4*)sh_h;
        #pragma unroll
        for (int i = 0; i < 32; ++i) {
            float4 hv = h4[i];
            acc0 = fdot2(w[4 * i + 0], __builtin_bit_cast(h2v, hv.x), acc0);
            acc1 = fdot2(w[4 * i + 1], __builtin_bit_cast(h2v, hv.y), acc1);
            acc2 = fdot2(w[4 * i + 2], __builtin_bit_cast(h2v, hv.z), acc2);
            acc3 = fdot2(w[4 * i + 3], __builtin_bit_cast(h2v, hv.w), acc3);
        }
        float gh = (acc0 + acc1) + (acc2 + acc3) + bj;

        if (j < 512) { a_lds[j] = gcur + gh; }
        else         { a_lds[j] = gh; gin_lds[j - 512] = gcur; }
        __syncthreads();   // gh/gi visible

        if (j < 256) {
            float r = 1.f / (1.f + expf(-a_lds[j]));
            float z = 1.f / (1.f + expf(-a_lds[256 + j]));
            float n = tanhf(gin_lds[j] + r * a_lds[512 + j]);
            hu = (1.f - z) * n + z * hu;
            sh_h[j] = (_Float16)hu;
            ho[(long)p * 256 + j] = (_Float16)hu;
        }
        __syncthreads();   // new h visible

        gcur = gnxt;
        p += dir;
    }
}

// ---------------- LayerNorm over H=256, wave per row ------------------------------
__global__ __launch_bounds__(256) void k_ln(
    const float* __restrict__ pre, const float* __restrict__ g,
    const float* __restrict__ b, float* __restrict__ out)
{
    const long row = (long)blockIdx.x * 4 + (threadIdx.x >> 6);
    const int lane = threadIdx.x & 63;
    const float4 v = *(const float4*)&pre[row * 256 + lane * 4];
    float s  = v.x + v.y + v.z + v.w;
    float s2 = v.x * v.x + v.y * v.y + v.z * v.z + v.w * v.w;
    #pragma unroll
    for (int off = 32; off > 0; off >>= 1) {
        s  += __shfl_xor(s, off);
        s2 += __shfl_xor(s2, off);
    }
    const float mu  = s * (1.f / 256.f);
    const float var = s2 * (1.f / 256.f) - mu * mu;
    const float inv = rsqrtf(var + 1e-5f);
    const float4 gg = *(const float4*)&g[lane * 4];
    const float4 bb = *(const float4*)&b[lane * 4];
    float4 o;
    o.x = (v.x - mu) * inv * gg.x + bb.x;
    o.y = (v.y - mu) * inv * gg.y + bb.y;
    o.z = (v.z - mu) * inv * gg.z + bb.z;
    o.w = (v.w - mu) * inv * gg.w + bb.w;
    *(float4*)&out[row * 256 + lane * 4] = o;
}

extern "C" void kernel_launch(void* const* d_in, const int* in_sizes, int n_in,
                              void* d_out, int out_size, void* d_ws, size_t ws_size,
                              hipStream_t stream)
{
    const float* x       = (const float*)d_in[0];
    const float* f_lin_W = (const float*)d_in[1];
    const float* f_lin_b = (const float*)d_in[2];
    const float* f_W_ih  = (const float*)d_in[3];
    const float* f_W_hh  = (const float*)d_in[4];
    const float* f_b_ih  = (const float*)d_in[5];
    const float* f_b_hh  = (const float*)d_in[6];
    const float* b_lin_W = (const float*)d_in[7];
    const float* b_lin_b = (const float*)d_in[8];
    const float* b_W_ih  = (const float*)d_in[9];
    const float* b_W_hh  = (const float*)d_in[10];
    const float* b_b_ih  = (const float*)d_in[11];
    const float* b_b_hh  = (const float*)d_in[12];
    const float* proj_W  = (const float*)d_in[13];
    const float* proj_b  = (const float*)d_in[14];
    const float* ln_g    = (const float*)d_in[15];
    const float* ln_bb   = (const float*)d_in[16];

    char* ws = (char*)d_ws;

    // ws layout: [gi_f 192MB | gi_b 192MB | h1 chunk buffers]
    // pre-LN fp32 (128MB) aliases gi_f region (gi dead by then).
    // h_out (f16, both dirs = 128MB) lives in d_out (fully overwritten by k_ln).
    const size_t GI_PER = (size_t)MTOT * 768 * 2;          // 201326592
    const size_t H1_OFF = 2 * GI_PER;                      // 402653184
    const size_t H1_FULL = (size_t)MTOT * 512 * 2 * 2;     // 268435456 (both dirs)
    int chunks = (ws_size >= H1_OFF + H1_FULL) ? 1
               : (ws_size >= H1_OFF + H1_FULL / 4) ? 4 : 8;
    const long MC = MTOT / chunks;

    _Float16* gif = (_Float16*)ws;
    _Float16* gib = (_Float16*)(ws + GI_PER);
    float*    pre = (float*)ws;
    _Float16* h1f = (_Float16*)(ws + H1_OFF);
    _Float16* h1b = h1f + MC * 512;

    _Float16* hof = (_Float16*)d_out;
    _Float16* hob = hof + MTOT * 256;

    for (int c = 0; c < chunks; ++c) {
        const long r0 = c * MC;
        k_gemm<0><<<dim3(MC / 64, 8),  256, 0, stream>>>(x + r0 * 256, nullptr, f_lin_W, f_lin_b, nullptr, h1f);
        k_gemm<0><<<dim3(MC / 64, 8),  256, 0, stream>>>(x + r0 * 256, nullptr, b_lin_W, b_lin_b, nullptr, h1b);
        k_gemm<1><<<dim3(MC / 64, 12), 256, 0, stream>>>(h1f, nullptr, f_W_ih, f_b_ih, nullptr, gif + r0 * 768);
        k_gemm<1><<<dim3(MC / 64, 12), 256, 0, stream>>>(h1b, nullptr, b_W_ih, b_b_ih, nullptr, gib + r0 * 768);
    }
    k_gru<<<256, 768, 0, stream>>>(gif, gib, f_W_hh, b_W_hh, f_b_hh, b_b_hh, hof, hob);
    k_gemm<2><<<dim3(MTOT / 64, 4), 256, 0, stream>>>(hof, hob, proj_W, proj_b, x, pre);
    k_ln<<<MTOT / 4, 256, 0, stream>>>(pre, ln_g, ln_bb, (float*)d_out);
}

// Round 2
// 2423.758 us; speedup vs baseline: 1.0794x; 1.0794x over previous
//
#include <hip/hip_runtime.h>
#include <cmath>

// BiDirectionalSpatialMamba: lin+GELU -> GRU(fwd & bwd over P) -> proj+residual -> LN
// B=8 T=16 P=1024 H=256, D_INNER=512, 3H=768. M = B*T*P = 131072 rows.

typedef _Float16 h8  __attribute__((ext_vector_type(8)));
typedef _Float16 h2v __attribute__((ext_vector_type(2)));
typedef float    f32x4 __attribute__((ext_vector_type(4)));

#define MTOT 131072L
#define PSEQ 1024

// guaranteed v_dot2_f32_f16, operands pinned to arch VGPRs
__device__ __forceinline__ void dot2_asm(float& acc, unsigned int a, unsigned int b) {
    asm("v_dot2_f32_f16 %0, %1, %2, %0" : "+v"(acc) : "v"(a), "v"(b));
}

__device__ __forceinline__ float fast_sigmoid(float x) {
    float e = __builtin_amdgcn_exp2f(-1.44269504089f * x);
    return __builtin_amdgcn_rcpf(1.f + e);
}
__device__ __forceinline__ float fast_tanh(float x) {
    float e = __builtin_amdgcn_exp2f(-2.88539008178f * x);
    return 2.f * __builtin_amdgcn_rcpf(1.f + e) - 1.f;
}

// ---------------- GEMM: C[M x N] = A[M x K] @ B[K x N] + bias, f16 MFMA ----------
// MODE 0: A fp32 (x),   K=256 N=512, epilogue GELU(exact) -> f16 (h1)
// MODE 1: A f16 (h1),   K=512 N=768, epilogue +b_ih       -> f16 (gi)
// MODE 2: A cat f16,    K=512 N=256, epilogue +b +x       -> f32 (pre-LN)
template <int MODE>
__global__ __launch_bounds__(256) void k_gemm(
    const void* __restrict__ Aa_, const void* __restrict__ Ab_,
    const float* __restrict__ B, const float* __restrict__ bias,
    const float* __restrict__ xres, void* __restrict__ out_)
{
    constexpr int K = (MODE == 0) ? 256 : 512;
    constexpr int N = (MODE == 0) ? 512 : (MODE == 1 ? 768 : 256);

    __shared__ __align__(16) _Float16 Al[64][40];  // [m][k], pad 32->40 (bank spread)
    __shared__ __align__(16) _Float16 Bl[64][40];  // [n][k]

    const int tid  = threadIdx.x;
    const int lane = tid & 63;
    const int wave = tid >> 6;
    const int wm = wave >> 1, wn = wave & 1;
    const long bm0 = (long)blockIdx.x * 64;
    const int  bn0 = blockIdx.y * 64;

    const int sm  = tid >> 2;          // A staging: row
    const int ska = (tid & 3) * 8;     // A staging: k offset
    const int sn  = tid & 63;          // B staging: col
    const int skb = (tid >> 6) * 8;    // B staging: k offset

    f32x4 acc[2][2] = {};

    for (int kt = 0; kt < K / 32; ++kt) {
        h8 av;
        if constexpr (MODE == 0) {
            const float* ap = (const float*)Aa_ + (bm0 + sm) * 256 + kt * 32 + ska;
            #pragma unroll
            for (int i = 0; i < 8; ++i) av[i] = (_Float16)ap[i];
        } else if constexpr (MODE == 1) {
            av = *(const h8*)((const _Float16*)Aa_ + (bm0 + sm) * 512 + kt * 32 + ska);
        } else {
            const _Float16* src = (kt < 8) ? (const _Float16*)Aa_ : (const _Float16*)Ab_;
            av = *(const h8*)(src + (bm0 + sm) * 256 + (kt & 7) * 32 + ska);
        }
        *(h8*)&Al[sm][ska] = av;

        h8 bv;
        #pragma unroll
        for (int i = 0; i < 8; ++i)
            bv[i] = (_Float16)B[(long)(kt * 32 + skb + i) * N + bn0 + sn];
        *(h8*)&Bl[sn][skb] = bv;

        __syncthreads();

        const int fr = lane & 15, fg = lane >> 4;
        h8 a0 = *(const h8*)&Al[wm * 32 +      fr][fg * 8];
        h8 a1 = *(const h8*)&Al[wm * 32 + 16 + fr][fg * 8];
        h8 b0 = *(const h8*)&Bl[wn * 32 +      fr][fg * 8];
        h8 b1 = *(const h8*)&Bl[wn * 32 + 16 + fr][fg * 8];
        acc[0][0] = __builtin_amdgcn_mfma_f32_16x16x32_f16(a0, b0, acc[0][0], 0, 0, 0);
        acc[0][1] = __builtin_amdgcn_mfma_f32_16x16x32_f16(a0, b1, acc[0][1], 0, 0, 0);
        acc[1][0] = __builtin_amdgcn_mfma_f32_16x16x32_f16(a1, b0, acc[1][0], 0, 0, 0);
        acc[1][1] = __builtin_amdgcn_mfma_f32_16x16x32_f16(a1, b1, acc[1][1], 0, 0, 0);

        __syncthreads();
    }

    const int fr = lane & 15, fg = lane >> 4;
    #pragma unroll
    for (int fm = 0; fm < 2; ++fm)
    #pragma unroll
    for (int fn = 0; fn < 2; ++fn)
    #pragma unroll
    for (int r = 0; r < 4; ++r) {
        long row = bm0 + wm * 32 + fm * 16 + fg * 4 + r;
        int  col = bn0 + wn * 32 + fn * 16 + fr;
        float v = acc[fm][fn][r] + bias[col];
        if constexpr (MODE == 0) {
            v = 0.5f * v * (1.0f + erff(v * 0.70710678118654752f));
            ((_Float16*)out_)[row * (long)N + col] = (_Float16)v;
        } else if constexpr (MODE == 1) {
            ((_Float16*)out_)[row * (long)N + col] = (_Float16)v;
        } else {
            v += xres[row * 256 + col];
            ((float*)out_)[row * 256 + col] = v;
        }
    }
}

// ---------------- GRU recurrence: 256 blocks = 128 seq x 2 directions ------------
// 768 threads: thread j owns column j of W_hh (128 packed half2, pinned in arch
// VGPRs via the inline-asm dot2 "v" constraints). h (256 f16) broadcast from LDS.
// amdgpu_waves_per_eu(3,3): 12-wave block -> exactly 3 waves/SIMD -> 170-reg budget;
// stops the allocator from targeting 6 waves/EU (which gave VGPR=84 + AGPR shuffling).
__global__ __launch_bounds__(768) __attribute__((amdgpu_waves_per_eu(3, 3)))
void k_gru(
    const _Float16* __restrict__ gif, const _Float16* __restrict__ gib,
    const float* __restrict__ Whhf, const float* __restrict__ Whhb,
    const float* __restrict__ bhhf, const float* __restrict__ bhhb,
    _Float16* __restrict__ hof, _Float16* __restrict__ hob)
{
    const int bid = blockIdx.x;
    const int branch = bid & 1;
    const int seq = bid >> 1;
    const int j = threadIdx.x;

    const _Float16* gi = (branch ? gib : gif) + (long)seq * PSEQ * 768;
    const float* Whh = branch ? Whhb : Whhf;
    const float* bhh = branch ? bhhb : bhhf;
    _Float16* ho = (branch ? hob : hof) + (long)seq * PSEQ * 256;

    unsigned int w[128];
    #pragma unroll
    for (int kk = 0; kk < 128; ++kk) {
        h2v t;
        t[0] = (_Float16)Whh[(2 * kk) * 768 + j];
        t[1] = (_Float16)Whh[(2 * kk + 1) * 768 + j];
        w[kk] = __builtin_bit_cast(unsigned int, t);
    }
    const float bj = bhh[j];

    __shared__ __align__(16) _Float16 sh_h[256];
    __shared__ float a_lds[768];
    __shared__ float gin_lds[256];

    if (j < 256) sh_h[j] = (_Float16)0.f;
    __syncthreads();

    const int dir = branch ? -1 : 1;
    int p = branch ? (PSEQ - 1) : 0;
    float gcur = (float)gi[(long)p * 768 + j];
    float hu = 0.f;

    for (int step = 0; step < PSEQ; ++step) {
        float gnxt = 0.f;
        if (step < PSEQ - 1) gnxt = (float)gi[(long)(p + dir) * 768 + j];

        float acc0 = 0.f, acc1 = 0.f, acc2 = 0.f, acc3 = 0.f;
        const uint4* h4 = (const uint4*)sh_h;
        #pragma unroll
        for (int i = 0; i < 32; ++i) {
            uint4 hv = h4[i];
            dot2_asm(acc0, w[4 * i + 0], hv.x);
            dot2_asm(acc1, w[4 * i + 1], hv.y);
            dot2_asm(acc2, w[4 * i + 2], hv.z);
            dot2_asm(acc3, w[4 * i + 3], hv.w);
        }
        float gh = (acc0 + acc1) + (acc2 + acc3) + bj;

        if (j < 512) { a_lds[j] = gcur + gh; }
        else         { a_lds[j] = gh; gin_lds[j - 512] = gcur; }
        __syncthreads();   // gh/gi visible

        if (j < 256) {
            float r = fast_sigmoid(a_lds[j]);
            float z = fast_sigmoid(a_lds[256 + j]);
            float n = fast_tanh(gin_lds[j] + r * a_lds[512 + j]);
            hu = fmaf(z, hu - n, n);          // (1-z)*n + z*hu
            sh_h[j] = (_Float16)hu;
            ho[(long)p * 256 + j] = (_Float16)hu;
        }
        __syncthreads();   // new h visible

        gcur = gnxt;
        p += dir;
    }
}

// ---------------- LayerNorm over H=256, wave per row ------------------------------
__global__ __launch_bounds__(256) void k_ln(
    const float* __restrict__ pre, const float* __restrict__ g,
    const float* __restrict__ b, float* __restrict__ out)
{
    const long row = (long)blockIdx.x * 4 + (threadIdx.x >> 6);
    const int lane = threadIdx.x & 63;
    const float4 v = *(const float4*)&pre[row * 256 + lane * 4];
    float s  = v.x + v.y + v.z + v.w;
    float s2 = v.x * v.x + v.y * v.y + v.z * v.z + v.w * v.w;
    #pragma unroll
    for (int off = 32; off > 0; off >>= 1) {
        s  += __shfl_xor(s, off);
        s2 += __shfl_xor(s2, off);
    }
    const float mu  = s * (1.f / 256.f);
    const float var = s2 * (1.f / 256.f) - mu * mu;
    const float inv = rsqrtf(var + 1e-5f);
    const float4 gg = *(const float4*)&g[lane * 4];
    const float4 bb = *(const float4*)&b[lane * 4];
    float4 o;
    o.x = (v.x - mu) * inv * gg.x + bb.x;
    o.y = (v.y - mu) * inv * gg.y + bb.y;
    o.z = (v.z - mu) * inv * gg.z + bb.z;
    o.w = (v.w - mu) * inv * gg.w + bb.w;
    *(float4*)&out[row * 256 + lane * 4] = o;
}

extern "C" void kernel_launch(void* const* d_in, const int* in_sizes, int n_in,
                              void* d_out, int out_size, void* d_ws, size_t ws_size,
                              hipStream_t stream)
{
    const float* x       = (const float*)d_in[0];
    const float* f_lin_W = (const float*)d_in[1];
    const float* f_lin_b = (const float*)d_in[2];
    const float* f_W_ih  = (const float*)d_in[3];
    const float* f_W_hh  = (const float*)d_in[4];
    const float* f_b_ih  = (const float*)d_in[5];
    const float* f_b_hh  = (const float*)d_in[6];
    const float* b_lin_W = (const float*)d_in[7];
    const float* b_lin_b = (const float*)d_in[8];
    const float* b_W_ih  = (const float*)d_in[9];
    const float* b_W_hh  = (const float*)d_in[10];
    const float* b_b_ih  = (const float*)d_in[11];
    const float* b_b_hh  = (const float*)d_in[12];
    const float* proj_W  = (const float*)d_in[13];
    const float* proj_b  = (const float*)d_in[14];
    const float* ln_g    = (const float*)d_in[15];
    const float* ln_bb   = (const float*)d_in[16];

    char* ws = (char*)d_ws;

    // ws layout: [gi_f 192MB | gi_b 192MB | h1 chunk buffers]
    // pre-LN fp32 (128MB) aliases gi_f region (gi dead by then).
    // h_out (f16, both dirs = 128MB) lives in d_out (fully overwritten by k_ln).
    const size_t GI_PER = (size_t)MTOT * 768 * 2;          // 201326592
    const size_t H1_OFF = 2 * GI_PER;                      // 402653184
    const size_t H1_FULL = (size_t)MTOT * 512 * 2 * 2;     // 268435456 (both dirs)
    int chunks = (ws_size >= H1_OFF + H1_FULL) ? 1
               : (ws_size >= H1_OFF + H1_FULL / 4) ? 4 : 8;
    const long MC = MTOT / chunks;

    _Float16* gif = (_Float16*)ws;
    _Float16* gib = (_Float16*)(ws + GI_PER);
    float*    pre = (float*)ws;
    _Float16* h1f = (_Float16*)(ws + H1_OFF);
    _Float16* h1b = h1f + MC * 512;

    _Float16* hof = (_Float16*)d_out;
    _Float16* hob = hof + MTOT * 256;

    for (int c = 0; c < chunks; ++c) {
        const long r0 = c * MC;
        k_gemm<0><<<dim3(MC / 64, 8),  256, 0, stream>>>(x + r0 * 256, nullptr, f_lin_W, f_lin_b, nullptr, h1f);
        k_gemm<0><<<dim3(MC / 64, 8),  256, 0, stream>>>(x + r0 * 256, nullptr, b_lin_W, b_lin_b, nullptr, h1b);
        k_gemm<1><<<dim3(MC / 64, 12), 256, 0, stream>>>(h1f, nullptr, f_W_ih, f_b_ih, nullptr, gif + r0 * 768);
        k_gemm<1><<<dim3(MC / 64, 12), 256, 0, stream>>>(h1b, nullptr, b_W_ih, b_b_ih, nullptr, gib + r0 * 768);
    }
    k_gru<<<256, 768, 0, stream>>>(gif, gib, f_W_hh, b_W_hh, f_b_hh, b_b_hh, hof, hob);
    k_gemm<2><<<dim3(MTOT / 64, 4), 256, 0, stream>>>(hof, hob, proj_W, proj_b, x, pre);
    k_ln<<<MTOT / 4, 256, 0, stream>>>(pre, ln_g, ln_bb, (float*)d_out);
}